// Round 16
// baseline (365.023 us; speedup 1.0000x reference)
//
#include <hip/hip_runtime.h>

typedef __attribute__((ext_vector_type(8))) short  s16x8;
typedef __attribute__((ext_vector_type(8))) unsigned short u16x8;
typedef __attribute__((ext_vector_type(4))) float  f32x4;

#define D_MODEL 1024
#define N_HEADS 16
#define D_HEAD  64
#define BATCH   2
#define SEQ     2048
#define M_TOK   4096   // BATCH*SEQ

// ---------------- ws layout (ushort element offsets) ----------------
#define OFF_XQ  0u            // 4M u16; reused for VhT after projections
#define OFF_XK  4194304u
#define OFF_XV  8388608u      // reused for mask bitmask after V projection
#define OFF_XC  12582912u
#define OFF_WT  16777216u     // 7 x 1048576 : Wq,Wqb,Wk,Wkg,Wv,Wvb,Wo (transposed [n][k])
#define OFF_QH  24117248u     // [B][H][T][64] bf16 (pre-scaled by log2e/8)
#define OFF_KH  28311552u
#define OFF_VH  32505856u
#define OFF_OH  36700160u     // [B*T][1024] bf16; ALSO sgT[n][m] before attn runs

__device__ __forceinline__ unsigned short f2bf(float f) {
    unsigned int u = __builtin_bit_cast(unsigned int, f);
    u += 0x7FFFu + ((u >> 16) & 1u);
    return (unsigned short)(u >> 16);
}

// single-instruction packed f32x2 -> bf16x2 (RNE); low half = a
__device__ __forceinline__ unsigned int cvtpk(float a, float b) {
    unsigned int r;
    asm("v_cvt_pk_bf16_f32 %0, %1, %2" : "=v"(r) : "v"(a), "v"(b));
    return r;
}

__device__ __forceinline__ float bf2f(unsigned short u) {
    return __builtin_bit_cast(float, (unsigned int)u << 16);
}

__device__ __forceinline__ void gload16(const void* g, void* l) {
    __builtin_amdgcn_global_load_lds(
        (const __attribute__((address_space(1))) unsigned int*)g,
        (__attribute__((address_space(3))) unsigned int*)l, 16, 0, 0);
}

__device__ __forceinline__ f32x4 mfma16(s16x8 a, s16x8 b, f32x4 c) {
    return __builtin_amdgcn_mfma_f32_16x16x32_bf16(a, b, c, 0, 0, 0);
}

__device__ __forceinline__ f32x4 zero4() {
    f32x4 z; z[0] = 0.f; z[1] = 0.f; z[2] = 0.f; z[3] = 0.f; return z;
}

// ---------------- conversion kernels ----------------
struct P4 { const float* p[4]; };
struct P7 { const float* p[7]; };

__global__ __launch_bounds__(256) void cvt4(P4 srcs, unsigned short* dst) {
    const int a = blockIdx.y;
    const float* s = srcs.p[a];
    unsigned short* d = dst + ((size_t)a << 22);
    const size_t i = (((size_t)blockIdx.x << 8) + threadIdx.x) << 3;
    const float4 v0 = *(const float4*)(s + i);
    const float4 v1 = *(const float4*)(s + i + 4);
    u16x8 o;
    o[0] = f2bf(v0.x); o[1] = f2bf(v0.y); o[2] = f2bf(v0.z); o[3] = f2bf(v0.w);
    o[4] = f2bf(v1.x); o[5] = f2bf(v1.y); o[6] = f2bf(v1.z); o[7] = f2bf(v1.w);
    *(u16x8*)(d + i) = o;
}

// transpose weights: Wt[n][k] = W[k][n], f32 -> bf16
__global__ __launch_bounds__(256) void wtr(P7 srcs, unsigned short* dst) {
    const int z = blockIdx.z;
    const float* W = srcs.p[z];
    unsigned short* Wt = dst + ((size_t)z << 20);
    __shared__ float T[32][33];
    const int t = threadIdx.x;
    const int r = t >> 3, c4 = (t & 7) << 2;
    const int kt = blockIdx.y << 5, nt = blockIdx.x << 5;
    const float4 v = *(const float4*)(W + ((size_t)(kt + r) << 10) + nt + c4);
    T[r][c4] = v.x; T[r][c4 + 1] = v.y; T[r][c4 + 2] = v.z; T[r][c4 + 3] = v.w;
    __syncthreads();
    ushort4 o;
    o.x = f2bf(T[c4 + 0][r]); o.y = f2bf(T[c4 + 1][r]);
    o.z = f2bf(T[c4 + 2][r]); o.w = f2bf(T[c4 + 3][r]);
    *(ushort4*)(Wt + ((size_t)(nt + r) << 10) + kt + c4) = o;
}

// V head-transpose: VhT[bh][d][s] = Vh[bh][s][d]
__global__ __launch_bounds__(256) void vtr(const unsigned short* __restrict__ Vh,
                                           unsigned short* __restrict__ VhT) {
    __shared__ unsigned short T[64][72];
    const int bh = blockIdx.y, s0 = blockIdx.x << 6;
    const unsigned short* src = Vh + ((size_t)bh * 2048 + s0) * 64;
    unsigned short* dst = VhT + (size_t)bh * 64 * 2048 + s0;
    const int t = threadIdx.x;
    const int r = t >> 3, c0 = (t & 7) << 3;
    #pragma unroll
    for (int it = 0; it < 2; ++it) {
        const int rr = it * 32 + r;
        const u16x8 v = *(const u16x8*)(src + (size_t)rr * 64 + c0);
        #pragma unroll
        for (int i = 0; i < 8; ++i) T[c0 + i][rr] = v[i];
    }
    __syncthreads();
    #pragma unroll
    for (int it = 0; it < 2; ++it) {
        const int rr = it * 32 + r;
        u16x8 o;
        #pragma unroll
        for (int i = 0; i < 8; ++i) o[i] = T[rr][c0 + i];
        *(u16x8*)(dst + (size_t)rr * 2048 + c0) = o;
    }
}

// pack mask to bits: bit i of mb[w] = mask[w*64+i] != 0. Autodetect int32 vs byte.
__global__ __launch_bounds__(256) void mpack(const unsigned char* __restrict__ maskp,
                                             unsigned long long* __restrict__ mb) {
    const unsigned int probe = ((const unsigned int*)maskp)[threadIdx.x & 63];
    const bool isInt = __all(probe <= 1u);
    const size_t i = ((size_t)blockIdx.x << 8) + threadIdx.x;
    bool v;
    if (isInt) v = ((const int*)maskp)[i] != 0;
    else       v = maskp[i] != 0;
    const unsigned long long bal = __ballot(v);
    if ((threadIdx.x & 63) == 0) mb[i >> 6] = bal;
}

// ---------------- gate-sigmoid GEMM: sgT[n][m] = bf16(sigmoid(Xc@Wkg + bkg)) ----------
// 128x64 tile, K=1024 (32 steps), 2-phase dbuf.
__global__ __launch_bounds__(256) void proj_gate_sig(
    const unsigned short* __restrict__ A, const unsigned short* __restrict__ Bt,
    const float* __restrict__ bias, unsigned short* __restrict__ sgT)
{
    __shared__ unsigned short Al[2][128 * 32];
    __shared__ unsigned short Bl[2][64 * 32];
    const int tid = threadIdx.x;
    const int wid = tid >> 6, lane = tid & 63;
    const int lo = lane & 15, hi = lane >> 4;
    const int wr = wid >> 1, wc = wid & 1;
    const int m0 = blockIdx.y << 7, n0 = blockIdx.x << 6;

    auto stageT = [&](int t) {
        const int bufi = t & 1;
        const int k0 = t << 5;
        #pragma unroll
        for (int it = 0; it < 2; ++it) {
            const int c = it * 256 + tid;
            const int r = c >> 2, j = c & 3;
            gload16(A + ((size_t)(m0 + r) << 10) + k0 + j * 8, &Al[bufi][c * 8]);
        }
        const int rb = tid >> 2, jb = tid & 3;
        gload16(Bt + ((size_t)(n0 + rb) << 10) + k0 + jb * 8, &Bl[bufi][tid * 8]);
    };

    f32x4 acc[4][2];
    #pragma unroll
    for (int i = 0; i < 4; ++i)
        #pragma unroll
        for (int j = 0; j < 2; ++j) acc[i][j] = zero4();

    stageT(0);
    for (int t = 0; t < 32; ++t) {
        __syncthreads();
        if (t < 31) stageT(t + 1);
        const int bufi = t & 1;
        s16x8 af[4], bfr[2];
        #pragma unroll
        for (int mi = 0; mi < 4; ++mi)
            af[mi] = *(const s16x8*)&Al[bufi][(wr * 64 + mi * 16 + lo) * 32 + hi * 8];
        #pragma unroll
        for (int ni = 0; ni < 2; ++ni)
            bfr[ni] = *(const s16x8*)&Bl[bufi][(wc * 32 + ni * 16 + lo) * 32 + hi * 8];
        __builtin_amdgcn_s_setprio(1);
        #pragma unroll
        for (int mi = 0; mi < 4; ++mi)
            #pragma unroll
            for (int ni = 0; ni < 2; ++ni)
                acc[mi][ni] = mfma16(af[mi], bfr[ni], acc[mi][ni]);
        __builtin_amdgcn_s_setprio(0);
    }

    #pragma unroll
    for (int mi = 0; mi < 4; ++mi)
        #pragma unroll
        for (int ni = 0; ni < 2; ++ni) {
            const int n = n0 + wc * 32 + ni * 16 + lo;
            const float bb = bias[n];
            const int mb = m0 + wr * 64 + mi * 16 + hi * 4;
            ushort4 o;
            unsigned short* op = (unsigned short*)&o;
            #pragma unroll
            for (int reg = 0; reg < 4; ++reg) {
                const float g = acc[mi][ni][reg] + bb;
                op[reg] = f2bf(1.0f / (1.0f + __expf(-g)));
            }
            *(ushort4*)(sgT + (size_t)n * 4096 + mb) = o;
        }
}

// ---------------- fused projection GEMMs (m97 128x128, uniform single acc) ------------
struct ProjDesc {
    const unsigned short *A0, *A1, *B0, *B1;
    const float *b0, *b1;
    unsigned short* dst;
    float scale;
    int gate;
    int nsteps;
};
struct ProjArgs { ProjDesc d[3]; };

__global__ __launch_bounds__(256) void proj_all(ProjArgs pa, const unsigned short* __restrict__ sgT) {
    const ProjDesc P = pa.d[blockIdx.z];
    __shared__ unsigned short Al[2][128 * 32];   // 2 x 8 KB
    __shared__ unsigned short Bl[2][128 * 32];   // 2 x 8 KB
    const int tid = threadIdx.x;
    const int wid = tid >> 6, lane = tid & 63;
    const int lo = lane & 15, hi = lane >> 4;
    const int wr = wid >> 1, wc = wid & 1;
    const int m0 = blockIdx.y << 7, n0 = blockIdx.x << 7;

    auto stageT = [&](int t) {
        const int bufi = t & 1;
        const unsigned short* As = (t < 32) ? P.A0 : P.A1;
        const unsigned short* Bs = (t < 32) ? P.B0 : P.B1;
        const int k0 = (t & 31) << 5;
        #pragma unroll
        for (int it = 0; it < 2; ++it) {
            const int c = it * 256 + tid;
            const int r = c >> 2, j = c & 3;
            gload16(As + ((size_t)(m0 + r) << 10) + k0 + j * 8, &Al[bufi][c * 8]);
            gload16(Bs + ((size_t)(n0 + r) << 10) + k0 + j * 8, &Bl[bufi][c * 8]);
        }
    };

    f32x4 acc[4][4];
    #pragma unroll
    for (int i = 0; i < 4; ++i)
        #pragma unroll
        for (int j = 0; j < 4; ++j) acc[i][j] = zero4();

    const int nsteps = P.nsteps;
    stageT(0);
    for (int t = 0; t < nsteps; ++t) {
        __syncthreads();
        if (t + 1 < nsteps) stageT(t + 1);
        const int bufi = t & 1;
        s16x8 af[4], bfr[4];
        #pragma unroll
        for (int mi = 0; mi < 4; ++mi)
            af[mi] = *(const s16x8*)&Al[bufi][(wr * 64 + mi * 16 + lo) * 32 + hi * 8];
        #pragma unroll
        for (int ni = 0; ni < 4; ++ni)
            bfr[ni] = *(const s16x8*)&Bl[bufi][(wc * 64 + ni * 16 + lo) * 32 + hi * 8];
        __builtin_amdgcn_s_setprio(1);
        #pragma unroll
        for (int mi = 0; mi < 4; ++mi)
            #pragma unroll
            for (int ni = 0; ni < 4; ++ni)
                acc[mi][ni] = mfma16(af[mi], bfr[ni], acc[mi][ni]);
        __builtin_amdgcn_s_setprio(0);
    }

    #pragma unroll
    for (int mi = 0; mi < 4; ++mi)
        #pragma unroll
        for (int ni = 0; ni < 4; ++ni) {
            const int n = n0 + wc * 64 + ni * 16 + lo;
            const float b0 = P.b0[n];
            const float b1 = P.b1[n];
            const int h = n >> 6, d = n & 63;
            const int mb = m0 + wr * 64 + mi * 16 + hi * 4;
            ushort4 sgv;
            if (P.gate) sgv = *(const ushort4*)(sgT + (size_t)n * 4096 + mb);
            const unsigned short* sp = (const unsigned short*)&sgv;
            #pragma unroll
            for (int reg = 0; reg < 4; ++reg) {
                const int m = mb + reg;
                const int b = m >> 11, t = m & 2047;
                float val;
                if (P.gate) val = (acc[mi][ni][reg] + b0) * bf2f(sp[reg]);
                else        val = (acc[mi][ni][reg] + b0 + b1) * P.scale;
                P.dst[((size_t)((b * 16 + h) * 2048 + t) << 6) + d] = f2bf(val);
            }
        }
}

// out0 = Oh @ Wo + bo  (f32 output), 128x64 tile, 2-phase double-buffered
__global__ __launch_bounds__(256) void gemm_out(
    const unsigned short* __restrict__ A, const unsigned short* __restrict__ Bt,
    const float* __restrict__ bias, float* __restrict__ out)
{
    __shared__ unsigned short Al[2][128 * 32];
    __shared__ unsigned short Bl[2][64 * 32];
    const int tid = threadIdx.x;
    const int wid = tid >> 6, lane = tid & 63;
    const int lo = lane & 15, hi = lane >> 4;
    const int wr = wid >> 1, wc = wid & 1;
    const int m0 = blockIdx.y << 7, n0 = blockIdx.x << 6;

    auto stageT = [&](int t) {
        const int bufi = t & 1;
        const int k0 = t << 5;
        #pragma unroll
        for (int it = 0; it < 2; ++it) {
            const int c = it * 256 + tid;
            const int r = c >> 2, j = c & 3;
            gload16(A + ((size_t)(m0 + r) << 10) + k0 + j * 8, &Al[bufi][c * 8]);
        }
        const int rb = tid >> 2, jb = tid & 3;
        gload16(Bt + ((size_t)(n0 + rb) << 10) + k0 + jb * 8, &Bl[bufi][tid * 8]);
    };

    f32x4 acc[4][2];
    #pragma unroll
    for (int i = 0; i < 4; ++i)
        #pragma unroll
        for (int j = 0; j < 2; ++j) acc[i][j] = zero4();

    stageT(0);
    for (int t = 0; t < 32; ++t) {
        __syncthreads();
        if (t < 31) stageT(t + 1);
        const int bufi = t & 1;
        s16x8 af[4], bfr[2];
        #pragma unroll
        for (int mi = 0; mi < 4; ++mi)
            af[mi] = *(const s16x8*)&Al[bufi][(wr * 64 + mi * 16 + lo) * 32 + hi * 8];
        #pragma unroll
        for (int ni = 0; ni < 2; ++ni)
            bfr[ni] = *(const s16x8*)&Bl[bufi][(wc * 32 + ni * 16 + lo) * 32 + hi * 8];
        __builtin_amdgcn_s_setprio(1);
        #pragma unroll
        for (int mi = 0; mi < 4; ++mi)
            #pragma unroll
            for (int ni = 0; ni < 2; ++ni)
                acc[mi][ni] = mfma16(af[mi], bfr[ni], acc[mi][ni]);
        __builtin_amdgcn_s_setprio(0);
    }

    #pragma unroll
    for (int mi = 0; mi < 4; ++mi)
        #pragma unroll
        for (int ni = 0; ni < 2; ++ni) {
            const int n = n0 + wc * 32 + ni * 16 + lo;
            const float bb = bias[n];
            #pragma unroll
            for (int reg = 0; reg < 4; ++reg) {
                const int m = m0 + wr * 64 + mi * 16 + hi * 4 + reg;
                out[((size_t)m << 10) + n] = acc[mi][ni][reg] + bb;
            }
        }
}

// ---------------- fused attention (QBLK=128 via 8 waves x 16 q; per-wave code = R5) ----
// 512 blocks (XCD-chunked), 512 threads. LDS 48KB -> 3 blocks/CU = 24 waves (75% occ).
// Each K/V tile staged once serves 128 q-rows (2x amortization vs QBLK=64).
__global__ __launch_bounds__(512, 4) void attn_fused(
    const unsigned short* __restrict__ Qh, const unsigned short* __restrict__ Kh,
    const unsigned short* __restrict__ VhT, const unsigned long long* __restrict__ mbits,
    float* __restrict__ attnW, unsigned short* __restrict__ Oh)
{
    __shared__ unsigned short Ks[2][4096];   // [64 s][64 d], 16B chunks XOR-swizzled by row&7
    __shared__ unsigned short Vs[2][4096];   // [64 d][64 s], same swizzle
    __shared__ unsigned short Ps[8][1024];   // per-wave P^T [16 q][64 s]

    const int tid = threadIdx.x;
    const int wid = tid >> 6, lane = tid & 63;
    const int lo = lane & 15, hi = lane >> 4;

    const int wg = blockIdx.x;                 // 512 blocks
    const int gid = (wg & 7) * 64 + (wg >> 3); // XCD-chunked
    const int bh = gid >> 4, lt = gid & 15;
    const int b = bh >> 4, hh = bh & 15;
    const int l0 = lt << 7;

    const unsigned short* Qp = Qh + ((size_t)bh * 2048 + l0) * 64;
    const unsigned short* Kp = Kh + (size_t)bh * 2048 * 64;
    const unsigned short* Vp = VhT + (size_t)bh * 64 * 2048;

    const int q = wid * 16 + lo;   // this thread's q row (0..127)
    float* Wrow = attnW + ((size_t)bh * 2048 + l0 + q) * 2048 + hi * 4;
    const unsigned long long* mq = mbits + ((size_t)b * 2048 + l0 + q) * 32;

    // Q fragment (B-operand): rows q, pre-scaled by log2e/8 at projection
    s16x8 qf[2];
    {
        const unsigned short* qr = Qp + (size_t)q * 64 + hi * 8;
        qf[0] = *(const s16x8*)qr;
        qf[1] = *(const s16x8*)(qr + 32);
    }

    auto stageK = [&](int st, int bufi) {      // 512 chunks, 1 per thread
        const unsigned short* src = Kp + (size_t)(st << 6) * 64;
        const int r = tid >> 3, j = tid & 7;
        gload16(src + (size_t)r * 64 + ((j ^ (r & 7)) << 3), &Ks[bufi][tid * 8]);
    };
    auto stageV = [&](int st, int bufi) {
        const unsigned short* src = Vp + (st << 6);
        const int r = tid >> 3, j = tid & 7;
        gload16(src + (size_t)r * 2048 + ((j ^ (r & 7)) << 3), &Vs[bufi][tid * 8]);
    };

    // ================= pass 0: row sums of 2^s ====
    float lsum = 0.f;
    stageK(0, 0);
    __syncthreads();
    for (int st = 0; st < 32; ++st) {
        const int cur = st & 1;
        if (st < 31) stageK(st + 1, cur ^ 1);

        const unsigned long long mrow = mq[st] >> (hi * 4);
        f32x4 sf[4];
        #pragma unroll
        for (int ni = 0; ni < 4; ++ni) sf[ni] = zero4();
        __builtin_amdgcn_s_setprio(1);
        #pragma unroll
        for (int ks = 0; ks < 2; ++ks)
            #pragma unroll
            for (int ni = 0; ni < 4; ++ni) {
                const int rn = ni * 16 + lo;
                const s16x8 kf = *(const s16x8*)&Ks[cur][rn * 64 + (((hi + ks * 4) ^ (rn & 7)) << 3)];
                sf[ni] = mfma16(kf, qf[ks], sf[ni]);   // S^T: row=s, col=q
            }
        __builtin_amdgcn_s_setprio(0);
        #pragma unroll
        for (int ni = 0; ni < 4; ++ni)
            #pragma unroll
            for (int reg = 0; reg < 4; ++reg) {
                const unsigned int bit = (unsigned int)(mrow >> (ni * 16 + reg)) & 1u;
                lsum += bit ? 0.f : exp2f(sf[ni][reg]);
            }
        __syncthreads();
    }
    lsum += __shfl_xor(lsum, 16);
    lsum += __shfl_xor(lsum, 32);
    const float il = 1.0f / lsum;

    // ================= pass 1: normalized weights + PV ================
    f32x4 oacc[4];
    #pragma unroll
    for (int nd = 0; nd < 4; ++nd) oacc[nd] = zero4();

    stageK(0, 0);
    stageV(0, 0);
    __syncthreads();
    for (int st = 0; st < 32; ++st) {
        const int cur = st & 1;
        if (st < 31) { stageK(st + 1, cur ^ 1); stageV(st + 1, cur ^ 1); }

        const unsigned long long mrow = mq[st] >> (hi * 4);
        f32x4 sf[4];
        #pragma unroll
        for (int ni = 0; ni < 4; ++ni) sf[ni] = zero4();
        __builtin_amdgcn_s_setprio(1);
        #pragma unroll
        for (int ks = 0; ks < 2; ++ks)
            #pragma unroll
            for (int ni = 0; ni < 4; ++ni) {
                const int rn = ni * 16 + lo;
                const s16x8 kf = *(const s16x8*)&Ks[cur][rn * 64 + (((hi + ks * 4) ^ (rn & 7)) << 3)];
                sf[ni] = mfma16(kf, qf[ks], sf[ni]);
            }
        __builtin_amdgcn_s_setprio(0);

        #pragma unroll
        for (int ni = 0; ni < 4; ++ni) {
            f32x4 wv;
            #pragma unroll
            for (int reg = 0; reg < 4; ++reg) {
                const unsigned int bit = (unsigned int)(mrow >> (ni * 16 + reg)) & 1u;
                const float e = bit ? 0.f : exp2f(sf[ni][reg]);
                wv[reg] = e * il;
            }
            __builtin_nontemporal_store(wv, (f32x4*)(Wrow + (size_t)st * 64 + ni * 16));
            const unsigned int p01 = cvtpk(wv[0], wv[1]);
            const unsigned int p23 = cvtpk(wv[2], wv[3]);
            *(uint2*)((char*)&Ps[wid][0] + lo * 128 + ((ni * 32 + hi * 8) ^ ((lo & 7) << 4))) =
                make_uint2(p01, p23);
        }

        // PV: O[q][d] += P[q][s] V[s][d]
        __builtin_amdgcn_s_setprio(1);
        #pragma unroll
        for (int ks = 0; ks < 2; ++ks) {
            const s16x8 pf = *(const s16x8*)((const char*)&Ps[wid][0] +
                lo * 128 + ((ks * 64 + hi * 16) ^ ((lo & 7) << 4)));
            #pragma unroll
            for (int nd = 0; nd < 4; ++nd) {
                const int rv = nd * 16 + lo;
                const s16x8 vf = *(const s16x8*)&Vs[cur][rv * 64 + (((hi + ks * 4) ^ (rv & 7)) << 3)];
                oacc[nd] = mfma16(pf, vf, oacc[nd]);
            }
        }
        __builtin_amdgcn_s_setprio(0);
        __syncthreads();
    }

    // ---- epilogue: Oh[b*2048 + l][h*64 + d] ----
    #pragma unroll
    for (int nd = 0; nd < 4; ++nd)
        #pragma unroll
        for (int reg = 0; reg < 4; ++reg) {
            const int rl = wid * 16 + hi * 4 + reg;
            const int d = nd * 16 + lo;
            Oh[((size_t)(b * 2048 + l0 + rl) << 10) + hh * 64 + d] = f2bf(oacc[nd][reg]);
        }
}

// ---------------- launch ----------------
extern "C" void kernel_launch(void* const* d_in, const int* in_sizes, int n_in,
                              void* d_out, int out_size, void* d_ws, size_t ws_size,
                              hipStream_t stream) {
    const float* queries = (const float*)d_in[0];
    const float* keys    = (const float*)d_in[1];
    const float* values  = (const float*)d_in[2];
    const unsigned char* mask = (const unsigned char*)d_in[3];
    const float* context = (const float*)d_in[4];
    const float* Wq  = (const float*)d_in[5];  const float* bq  = (const float*)d_in[6];
    const float* Wk  = (const float*)d_in[7];  const float* bk  = (const float*)d_in[8];
    const float* Wv  = (const float*)d_in[9];  const float* bv  = (const float*)d_in[10];
    const float* Wqb = (const float*)d_in[11]; const float* bqb = (const float*)d_in[12];
    const float* Wkg = (const float*)d_in[13]; const float* bkg = (const float*)d_in[14];
    const float* Wvb = (const float*)d_in[15]; const float* bvb = (const float*)d_in[16];
    const float* Wo  = (const float*)d_in[17]; const float* bo  = (const float*)d_in[18];

    unsigned short* ws = (unsigned short*)d_ws;
    unsigned short* xq = ws + OFF_XQ;
    unsigned short* xk = ws + OFF_XK;
    unsigned short* xv = ws + OFF_XV;
    unsigned short* xc = ws + OFF_XC;
    unsigned short* wt = ws + OFF_WT;
    unsigned short* Qh = ws + OFF_QH;
    unsigned short* Kh = ws + OFF_KH;
    unsigned short* Vh = ws + OFF_VH;
    unsigned short* Oh = ws + OFF_OH;
    unsigned short* sgT = ws + OFF_OH;                               // gate factors; Oh reused later
    unsigned short* VhT = ws + OFF_XQ;                               // reuse xq after projections
    unsigned long long* mbits = (unsigned long long*)(ws + OFF_XV);  // reuse xv after V proj

    float* out0  = (float*)d_out;
    float* attnW = out0 + 4194304;

    P4 acts; acts.p[0] = queries; acts.p[1] = keys; acts.p[2] = values; acts.p[3] = context;
    cvt4<<<dim3(2048, 4), 256, 0, stream>>>(acts, xq);

    P7 wts; wts.p[0] = Wq; wts.p[1] = Wqb; wts.p[2] = Wk; wts.p[3] = Wkg;
    wts.p[4] = Wv; wts.p[5] = Wvb; wts.p[6] = Wo;
    wtr<<<dim3(32, 32, 7), 256, 0, stream>>>(wts, wt);

    // gate factors first: sgT[n][m] = sigmoid(Xc@Wkg + bkg)
    proj_gate_sig<<<dim3(16, 32), 256, 0, stream>>>(xc, wt + 3u * 1048576u, bkg, sgT);

    ProjArgs pa;
    // z=0: Qh = ([Xq|Xc] @ [Wq;Wqb] + bq + bqb) * (0.125*log2e)  -> base-2 softmax
    pa.d[0] = { xq, xc, wt, wt + 1048576u, bq, bqb, Qh, 0.18033688f, 0, 64 };
    // z=1: Vh = [Xv|Xc] @ [Wv;Wvb] + bv + bvb
    pa.d[1] = { xv, xc, wt + 4u * 1048576u, wt + 5u * 1048576u, bv, bvb, Vh, 1.0f, 0, 64 };
    // z=2: Kh = (Xk@Wk + bk) * sgT   (A1=A0, B1=B0: staging branch-free, 32 steps)
    pa.d[2] = { xk, xk, wt + 2u * 1048576u, wt + 2u * 1048576u, bk, bk, Kh, 1.0f, 1, 32 };
    proj_all<<<dim3(8, 32, 3), 256, 0, stream>>>(pa, sgT);

    vtr<<<dim3(32, 32), 256, 0, stream>>>(Vh, VhT);            // xq region now free
    mpack<<<dim3(32768), 256, 0, stream>>>(mask, mbits);       // xv region now free

    attn_fused<<<dim3(512), 512, 0, stream>>>(Qh, Kh, VhT, mbits, attnW, Oh);

    gemm_out<<<dim3(16, 32), 256, 0, stream>>>(Oh, wt + 6u * 1048576u, bo, out0);
}

// Round 17
// 352.624 us; speedup vs baseline: 1.0352x; 1.0352x over previous
//
#include <hip/hip_runtime.h>

typedef __attribute__((ext_vector_type(8))) short  s16x8;
typedef __attribute__((ext_vector_type(8))) unsigned short u16x8;
typedef __attribute__((ext_vector_type(4))) float  f32x4;

#define D_MODEL 1024
#define N_HEADS 16
#define D_HEAD  64
#define BATCH   2
#define SEQ     2048
#define M_TOK   4096   // BATCH*SEQ

// ---------------- ws layout (ushort element offsets) ----------------
#define OFF_XQ  0u            // 4M u16; reused for VhT after projections
#define OFF_XK  4194304u
#define OFF_XV  8388608u      // reused for mask bitmask after V projection
#define OFF_XC  12582912u
#define OFF_WT  16777216u     // 7 x 1048576 : Wq,Wqb,Wk,Wkg,Wv,Wvb,Wo (transposed [n][k])
#define OFF_QH  24117248u     // [B][H][T][64] bf16 (pre-scaled by log2e/8)
#define OFF_KH  28311552u
#define OFF_VH  32505856u
#define OFF_OH  36700160u     // [B*T][1024] bf16; ALSO sgT[n][m] before attn runs

__device__ __forceinline__ unsigned short f2bf(float f) {
    unsigned int u = __builtin_bit_cast(unsigned int, f);
    u += 0x7FFFu + ((u >> 16) & 1u);
    return (unsigned short)(u >> 16);
}

// single-instruction packed f32x2 -> bf16x2 (RNE); low half = a
__device__ __forceinline__ unsigned int cvtpk(float a, float b) {
    unsigned int r;
    asm("v_cvt_pk_bf16_f32 %0, %1, %2" : "=v"(r) : "v"(a), "v"(b));
    return r;
}

__device__ __forceinline__ float bf2f(unsigned short u) {
    return __builtin_bit_cast(float, (unsigned int)u << 16);
}

__device__ __forceinline__ void gload16(const void* g, void* l) {
    __builtin_amdgcn_global_load_lds(
        (const __attribute__((address_space(1))) unsigned int*)g,
        (__attribute__((address_space(3))) unsigned int*)l, 16, 0, 0);
}

__device__ __forceinline__ f32x4 mfma16(s16x8 a, s16x8 b, f32x4 c) {
    return __builtin_amdgcn_mfma_f32_16x16x32_bf16(a, b, c, 0, 0, 0);
}

__device__ __forceinline__ f32x4 zero4() {
    f32x4 z; z[0] = 0.f; z[1] = 0.f; z[2] = 0.f; z[3] = 0.f; return z;
}

// ---------------- conversion kernels ----------------
struct P4 { const float* p[4]; };
struct P7 { const float* p[7]; };

__global__ __launch_bounds__(256) void cvt4(P4 srcs, unsigned short* dst) {
    const int a = blockIdx.y;
    const float* s = srcs.p[a];
    unsigned short* d = dst + ((size_t)a << 22);
    const size_t i = (((size_t)blockIdx.x << 8) + threadIdx.x) << 3;
    const float4 v0 = *(const float4*)(s + i);
    const float4 v1 = *(const float4*)(s + i + 4);
    u16x8 o;
    o[0] = f2bf(v0.x); o[1] = f2bf(v0.y); o[2] = f2bf(v0.z); o[3] = f2bf(v0.w);
    o[4] = f2bf(v1.x); o[5] = f2bf(v1.y); o[6] = f2bf(v1.z); o[7] = f2bf(v1.w);
    *(u16x8*)(d + i) = o;
}

// transpose weights: Wt[n][k] = W[k][n], f32 -> bf16
__global__ __launch_bounds__(256) void wtr(P7 srcs, unsigned short* dst) {
    const int z = blockIdx.z;
    const float* W = srcs.p[z];
    unsigned short* Wt = dst + ((size_t)z << 20);
    __shared__ float T[32][33];
    const int t = threadIdx.x;
    const int r = t >> 3, c4 = (t & 7) << 2;
    const int kt = blockIdx.y << 5, nt = blockIdx.x << 5;
    const float4 v = *(const float4*)(W + ((size_t)(kt + r) << 10) + nt + c4);
    T[r][c4] = v.x; T[r][c4 + 1] = v.y; T[r][c4 + 2] = v.z; T[r][c4 + 3] = v.w;
    __syncthreads();
    ushort4 o;
    o.x = f2bf(T[c4 + 0][r]); o.y = f2bf(T[c4 + 1][r]);
    o.z = f2bf(T[c4 + 2][r]); o.w = f2bf(T[c4 + 3][r]);
    *(ushort4*)(Wt + ((size_t)(nt + r) << 10) + kt + c4) = o;
}

// V head-transpose: VhT[bh][d][s] = Vh[bh][s][d]
__global__ __launch_bounds__(256) void vtr(const unsigned short* __restrict__ Vh,
                                           unsigned short* __restrict__ VhT) {
    __shared__ unsigned short T[64][72];
    const int bh = blockIdx.y, s0 = blockIdx.x << 6;
    const unsigned short* src = Vh + ((size_t)bh * 2048 + s0) * 64;
    unsigned short* dst = VhT + (size_t)bh * 64 * 2048 + s0;
    const int t = threadIdx.x;
    const int r = t >> 3, c0 = (t & 7) << 3;
    #pragma unroll
    for (int it = 0; it < 2; ++it) {
        const int rr = it * 32 + r;
        const u16x8 v = *(const u16x8*)(src + (size_t)rr * 64 + c0);
        #pragma unroll
        for (int i = 0; i < 8; ++i) T[c0 + i][rr] = v[i];
    }
    __syncthreads();
    #pragma unroll
    for (int it = 0; it < 2; ++it) {
        const int rr = it * 32 + r;
        u16x8 o;
        #pragma unroll
        for (int i = 0; i < 8; ++i) o[i] = T[rr][c0 + i];
        *(u16x8*)(dst + (size_t)rr * 2048 + c0) = o;
    }
}

// pack mask to bits: bit i of mb[w] = mask[w*64+i] != 0. Autodetect int32 vs byte.
__global__ __launch_bounds__(256) void mpack(const unsigned char* __restrict__ maskp,
                                             unsigned long long* __restrict__ mb) {
    const unsigned int probe = ((const unsigned int*)maskp)[threadIdx.x & 63];
    const bool isInt = __all(probe <= 1u);
    const size_t i = ((size_t)blockIdx.x << 8) + threadIdx.x;
    bool v;
    if (isInt) v = ((const int*)maskp)[i] != 0;
    else       v = maskp[i] != 0;
    const unsigned long long bal = __ballot(v);
    if ((threadIdx.x & 63) == 0) mb[i >> 6] = bal;
}

// ---------------- gate-sigmoid GEMM: sgT[n][m] = bf16(sigmoid(Xc@Wkg + bkg)) ----------
// 128x64 tile, K=1024 (32 steps), 2-phase dbuf.
__global__ __launch_bounds__(256) void proj_gate_sig(
    const unsigned short* __restrict__ A, const unsigned short* __restrict__ Bt,
    const float* __restrict__ bias, unsigned short* __restrict__ sgT)
{
    __shared__ unsigned short Al[2][128 * 32];
    __shared__ unsigned short Bl[2][64 * 32];
    const int tid = threadIdx.x;
    const int wid = tid >> 6, lane = tid & 63;
    const int lo = lane & 15, hi = lane >> 4;
    const int wr = wid >> 1, wc = wid & 1;
    const int m0 = blockIdx.y << 7, n0 = blockIdx.x << 6;

    auto stageT = [&](int t) {
        const int bufi = t & 1;
        const int k0 = t << 5;
        #pragma unroll
        for (int it = 0; it < 2; ++it) {
            const int c = it * 256 + tid;
            const int r = c >> 2, j = c & 3;
            gload16(A + ((size_t)(m0 + r) << 10) + k0 + j * 8, &Al[bufi][c * 8]);
        }
        const int rb = tid >> 2, jb = tid & 3;
        gload16(Bt + ((size_t)(n0 + rb) << 10) + k0 + jb * 8, &Bl[bufi][tid * 8]);
    };

    f32x4 acc[4][2];
    #pragma unroll
    for (int i = 0; i < 4; ++i)
        #pragma unroll
        for (int j = 0; j < 2; ++j) acc[i][j] = zero4();

    stageT(0);
    for (int t = 0; t < 32; ++t) {
        __syncthreads();
        if (t < 31) stageT(t + 1);
        const int bufi = t & 1;
        s16x8 af[4], bfr[2];
        #pragma unroll
        for (int mi = 0; mi < 4; ++mi)
            af[mi] = *(const s16x8*)&Al[bufi][(wr * 64 + mi * 16 + lo) * 32 + hi * 8];
        #pragma unroll
        for (int ni = 0; ni < 2; ++ni)
            bfr[ni] = *(const s16x8*)&Bl[bufi][(wc * 32 + ni * 16 + lo) * 32 + hi * 8];
        __builtin_amdgcn_s_setprio(1);
        #pragma unroll
        for (int mi = 0; mi < 4; ++mi)
            #pragma unroll
            for (int ni = 0; ni < 2; ++ni)
                acc[mi][ni] = mfma16(af[mi], bfr[ni], acc[mi][ni]);
        __builtin_amdgcn_s_setprio(0);
    }

    #pragma unroll
    for (int mi = 0; mi < 4; ++mi)
        #pragma unroll
        for (int ni = 0; ni < 2; ++ni) {
            const int n = n0 + wc * 32 + ni * 16 + lo;
            const float bb = bias[n];
            const int mb = m0 + wr * 64 + mi * 16 + hi * 4;
            ushort4 o;
            unsigned short* op = (unsigned short*)&o;
            #pragma unroll
            for (int reg = 0; reg < 4; ++reg) {
                const float g = acc[mi][ni][reg] + bb;
                op[reg] = f2bf(1.0f / (1.0f + __expf(-g)));
            }
            *(ushort4*)(sgT + (size_t)n * 4096 + mb) = o;
        }
}

// ---------------- fused projection GEMMs (m97 128x128, uniform single acc) ------------
// z0: Qh = ([Xq|Xc]@[Wq;Wqb] + bq+bqb)*scale (K=2048). z1: Vh likewise (K=2048).
// z2: Kh = (Xk@Wk + bk) * sgT  (K=1024; A1=A0,B1=B0 so staging is branch-free).
struct ProjDesc {
    const unsigned short *A0, *A1, *B0, *B1;
    const float *b0, *b1;
    unsigned short* dst;
    float scale;
    int gate;
    int nsteps;
};
struct ProjArgs { ProjDesc d[3]; };

__global__ __launch_bounds__(256) void proj_all(ProjArgs pa, const unsigned short* __restrict__ sgT) {
    const ProjDesc P = pa.d[blockIdx.z];
    __shared__ unsigned short Al[2][128 * 32];   // 2 x 8 KB
    __shared__ unsigned short Bl[2][128 * 32];   // 2 x 8 KB
    const int tid = threadIdx.x;
    const int wid = tid >> 6, lane = tid & 63;
    const int lo = lane & 15, hi = lane >> 4;
    const int wr = wid >> 1, wc = wid & 1;
    const int m0 = blockIdx.y << 7, n0 = blockIdx.x << 7;

    auto stageT = [&](int t) {
        const int bufi = t & 1;
        const unsigned short* As = (t < 32) ? P.A0 : P.A1;
        const unsigned short* Bs = (t < 32) ? P.B0 : P.B1;
        const int k0 = (t & 31) << 5;
        #pragma unroll
        for (int it = 0; it < 2; ++it) {
            const int c = it * 256 + tid;
            const int r = c >> 2, j = c & 3;
            gload16(As + ((size_t)(m0 + r) << 10) + k0 + j * 8, &Al[bufi][c * 8]);
            gload16(Bs + ((size_t)(n0 + r) << 10) + k0 + j * 8, &Bl[bufi][c * 8]);
        }
    };

    f32x4 acc[4][4];
    #pragma unroll
    for (int i = 0; i < 4; ++i)
        #pragma unroll
        for (int j = 0; j < 4; ++j) acc[i][j] = zero4();

    const int nsteps = P.nsteps;
    stageT(0);
    for (int t = 0; t < nsteps; ++t) {
        __syncthreads();
        if (t + 1 < nsteps) stageT(t + 1);
        const int bufi = t & 1;
        s16x8 af[4], bfr[4];
        #pragma unroll
        for (int mi = 0; mi < 4; ++mi)
            af[mi] = *(const s16x8*)&Al[bufi][(wr * 64 + mi * 16 + lo) * 32 + hi * 8];
        #pragma unroll
        for (int ni = 0; ni < 4; ++ni)
            bfr[ni] = *(const s16x8*)&Bl[bufi][(wc * 64 + ni * 16 + lo) * 32 + hi * 8];
        __builtin_amdgcn_s_setprio(1);
        #pragma unroll
        for (int mi = 0; mi < 4; ++mi)
            #pragma unroll
            for (int ni = 0; ni < 4; ++ni)
                acc[mi][ni] = mfma16(af[mi], bfr[ni], acc[mi][ni]);
        __builtin_amdgcn_s_setprio(0);
    }

    #pragma unroll
    for (int mi = 0; mi < 4; ++mi)
        #pragma unroll
        for (int ni = 0; ni < 4; ++ni) {
            const int n = n0 + wc * 64 + ni * 16 + lo;
            const float b0 = P.b0[n];
            const float b1 = P.b1[n];
            const int h = n >> 6, d = n & 63;
            const int mb = m0 + wr * 64 + mi * 16 + hi * 4;
            ushort4 sgv;
            if (P.gate) sgv = *(const ushort4*)(sgT + (size_t)n * 4096 + mb);
            const unsigned short* sp = (const unsigned short*)&sgv;
            #pragma unroll
            for (int reg = 0; reg < 4; ++reg) {
                const int m = mb + reg;
                const int b = m >> 11, t = m & 2047;
                float val;
                if (P.gate) val = (acc[mi][ni][reg] + b0) * bf2f(sp[reg]);
                else        val = (acc[mi][ni][reg] + b0 + b1) * P.scale;
                P.dst[((size_t)((b * 16 + h) * 2048 + t) << 6) + d] = f2bf(val);
            }
        }
}

// out0 = Oh @ Wo + bo  (f32 output), 128x64 tile, 2-phase double-buffered
__global__ __launch_bounds__(256) void gemm_out(
    const unsigned short* __restrict__ A, const unsigned short* __restrict__ Bt,
    const float* __restrict__ bias, float* __restrict__ out)
{
    __shared__ unsigned short Al[2][128 * 32];
    __shared__ unsigned short Bl[2][64 * 32];
    const int tid = threadIdx.x;
    const int wid = tid >> 6, lane = tid & 63;
    const int lo = lane & 15, hi = lane >> 4;
    const int wr = wid >> 1, wc = wid & 1;
    const int m0 = blockIdx.y << 7, n0 = blockIdx.x << 6;

    auto stageT = [&](int t) {
        const int bufi = t & 1;
        const int k0 = t << 5;
        #pragma unroll
        for (int it = 0; it < 2; ++it) {
            const int c = it * 256 + tid;
            const int r = c >> 2, j = c & 3;
            gload16(A + ((size_t)(m0 + r) << 10) + k0 + j * 8, &Al[bufi][c * 8]);
        }
        const int rb = tid >> 2, jb = tid & 3;
        gload16(Bt + ((size_t)(n0 + rb) << 10) + k0 + jb * 8, &Bl[bufi][tid * 8]);
    };

    f32x4 acc[4][2];
    #pragma unroll
    for (int i = 0; i < 4; ++i)
        #pragma unroll
        for (int j = 0; j < 2; ++j) acc[i][j] = zero4();

    stageT(0);
    for (int t = 0; t < 32; ++t) {
        __syncthreads();
        if (t < 31) stageT(t + 1);
        const int bufi = t & 1;
        s16x8 af[4], bfr[2];
        #pragma unroll
        for (int mi = 0; mi < 4; ++mi)
            af[mi] = *(const s16x8*)&Al[bufi][(wr * 64 + mi * 16 + lo) * 32 + hi * 8];
        #pragma unroll
        for (int ni = 0; ni < 2; ++ni)
            bfr[ni] = *(const s16x8*)&Bl[bufi][(wc * 32 + ni * 16 + lo) * 32 + hi * 8];
        __builtin_amdgcn_s_setprio(1);
        #pragma unroll
        for (int mi = 0; mi < 4; ++mi)
            #pragma unroll
            for (int ni = 0; ni < 2; ++ni)
                acc[mi][ni] = mfma16(af[mi], bfr[ni], acc[mi][ni]);
        __builtin_amdgcn_s_setprio(0);
    }

    #pragma unroll
    for (int mi = 0; mi < 4; ++mi)
        #pragma unroll
        for (int ni = 0; ni < 2; ++ni) {
            const int n = n0 + wc * 32 + ni * 16 + lo;
            const float bb = bias[n];
            #pragma unroll
            for (int reg = 0; reg < 4; ++reg) {
                const int m = m0 + wr * 64 + mi * 16 + hi * 4 + reg;
                out[((size_t)m << 10) + n] = acc[mi][ni][reg] + bb;
            }
        }
}

// ---------------- fused attention (R5/R11 structure: best measured) ----------
__global__ __launch_bounds__(256, 4) void attn_fused(
    const unsigned short* __restrict__ Qh, const unsigned short* __restrict__ Kh,
    const unsigned short* __restrict__ VhT, const unsigned long long* __restrict__ mbits,
    float* __restrict__ attnW, unsigned short* __restrict__ Oh)
{
    __shared__ unsigned short Ks[2][4096];   // [64 s][64 d], 16B chunks XOR-swizzled by row&7
    __shared__ unsigned short Vs[2][4096];   // [64 d][64 s], same swizzle
    __shared__ unsigned short Ps[4][1024];   // per-wave P^T [16 q][64 s]

    const int tid = threadIdx.x;
    const int wid = tid >> 6, lane = tid & 63;
    const int lo = lane & 15, hi = lane >> 4;

    const int wg = blockIdx.x;
    const int gid = (wg & 7) * 128 + (wg >> 3);
    const int bh = gid >> 5, lt = gid & 31;
    const int b = bh >> 4, hh = bh & 15;
    const int l0 = lt << 6;

    const unsigned short* Qp = Qh + ((size_t)bh * 2048 + l0) * 64;
    const unsigned short* Kp = Kh + (size_t)bh * 2048 * 64;
    const unsigned short* Vp = VhT + (size_t)bh * 64 * 2048;

    const int q = wid * 16 + lo;   // this thread's q row
    float* Wrow = attnW + ((size_t)bh * 2048 + l0 + q) * 2048 + hi * 4;
    const unsigned long long* mq = mbits + ((size_t)b * 2048 + l0 + q) * 32;

    // Q fragment (B-operand): rows q, pre-scaled by log2e/8 at projection
    s16x8 qf[2];
    {
        const unsigned short* qr = Qp + (size_t)q * 64 + hi * 8;
        qf[0] = *(const s16x8*)qr;
        qf[1] = *(const s16x8*)(qr + 32);
    }

    auto stageK = [&](int st, int bufi) {
        const unsigned short* src = Kp + (size_t)(st << 6) * 64;
        #pragma unroll
        for (int it = 0; it < 2; ++it) {
            const int c = it * 256 + tid;
            const int r = c >> 3, j = c & 7;
            gload16(src + (size_t)r * 64 + ((j ^ (r & 7)) << 3), &Ks[bufi][c * 8]);
        }
    };
    auto stageV = [&](int st, int bufi) {
        const unsigned short* src = Vp + (st << 6);
        #pragma unroll
        for (int it = 0; it < 2; ++it) {
            const int c = it * 256 + tid;
            const int r = c >> 3, j = c & 7;
            gload16(src + (size_t)r * 2048 + ((j ^ (r & 7)) << 3), &Vs[bufi][c * 8]);
        }
    };

    // ================= pass 0: row sums of 2^s ====
    float lsum = 0.f;
    stageK(0, 0);
    __syncthreads();
    for (int st = 0; st < 32; ++st) {
        const int cur = st & 1;
        if (st < 31) stageK(st + 1, cur ^ 1);

        const unsigned long long mrow = mq[st] >> (hi * 4);
        f32x4 sf[4];
        #pragma unroll
        for (int ni = 0; ni < 4; ++ni) sf[ni] = zero4();
        __builtin_amdgcn_s_setprio(1);
        #pragma unroll
        for (int ks = 0; ks < 2; ++ks)
            #pragma unroll
            for (int ni = 0; ni < 4; ++ni) {
                const int rn = ni * 16 + lo;
                const s16x8 kf = *(const s16x8*)&Ks[cur][rn * 64 + (((hi + ks * 4) ^ (rn & 7)) << 3)];
                sf[ni] = mfma16(kf, qf[ks], sf[ni]);   // S^T: row=s, col=q
            }
        __builtin_amdgcn_s_setprio(0);
        #pragma unroll
        for (int ni = 0; ni < 4; ++ni)
            #pragma unroll
            for (int reg = 0; reg < 4; ++reg) {
                const unsigned int bit = (unsigned int)(mrow >> (ni * 16 + reg)) & 1u;
                lsum += bit ? 0.f : exp2f(sf[ni][reg]);
            }
        __syncthreads();
    }
    lsum += __shfl_xor(lsum, 16);
    lsum += __shfl_xor(lsum, 32);
    const float il = 1.0f / lsum;

    // ================= pass 1: normalized weights + PV ================
    f32x4 oacc[4];
    #pragma unroll
    for (int nd = 0; nd < 4; ++nd) oacc[nd] = zero4();

    stageK(0, 0);
    stageV(0, 0);
    __syncthreads();
    for (int st = 0; st < 32; ++st) {
        const int cur = st & 1;
        if (st < 31) { stageK(st + 1, cur ^ 1); stageV(st + 1, cur ^ 1); }

        const unsigned long long mrow = mq[st] >> (hi * 4);
        f32x4 sf[4];
        #pragma unroll
        for (int ni = 0; ni < 4; ++ni) sf[ni] = zero4();
        __builtin_amdgcn_s_setprio(1);
        #pragma unroll
        for (int ks = 0; ks < 2; ++ks)
            #pragma unroll
            for (int ni = 0; ni < 4; ++ni) {
                const int rn = ni * 16 + lo;
                const s16x8 kf = *(const s16x8*)&Ks[cur][rn * 64 + (((hi + ks * 4) ^ (rn & 7)) << 3)];
                sf[ni] = mfma16(kf, qf[ks], sf[ni]);
            }
        __builtin_amdgcn_s_setprio(0);

        #pragma unroll
        for (int ni = 0; ni < 4; ++ni) {
            f32x4 wv;
            #pragma unroll
            for (int reg = 0; reg < 4; ++reg) {
                const unsigned int bit = (unsigned int)(mrow >> (ni * 16 + reg)) & 1u;
                const float e = bit ? 0.f : exp2f(sf[ni][reg]);
                wv[reg] = e * il;
            }
            __builtin_nontemporal_store(wv, (f32x4*)(Wrow + (size_t)st * 64 + ni * 16));
            const unsigned int p01 = cvtpk(wv[0], wv[1]);
            const unsigned int p23 = cvtpk(wv[2], wv[3]);
            *(uint2*)((char*)&Ps[wid][0] + lo * 128 + ((ni * 32 + hi * 8) ^ ((lo & 7) << 4))) =
                make_uint2(p01, p23);
        }

        // PV: O[q][d] += P[q][s] V[s][d]
        __builtin_amdgcn_s_setprio(1);
        #pragma unroll
        for (int ks = 0; ks < 2; ++ks) {
            const s16x8 pf = *(const s16x8*)((const char*)&Ps[wid][0] +
                lo * 128 + ((ks * 64 + hi * 16) ^ ((lo & 7) << 4)));
            #pragma unroll
            for (int nd = 0; nd < 4; ++nd) {
                const int rv = nd * 16 + lo;
                const s16x8 vf = *(const s16x8*)&Vs[cur][rv * 64 + (((hi + ks * 4) ^ (rv & 7)) << 3)];
                oacc[nd] = mfma16(pf, vf, oacc[nd]);
            }
        }
        __builtin_amdgcn_s_setprio(0);
        __syncthreads();
    }

    // ---- epilogue: Oh[b*2048 + l][h*64 + d] ----
    #pragma unroll
    for (int nd = 0; nd < 4; ++nd)
        #pragma unroll
        for (int reg = 0; reg < 4; ++reg) {
            const int rl = wid * 16 + hi * 4 + reg;
            const int d = nd * 16 + lo;
            Oh[((size_t)(b * 2048 + l0 + rl) << 10) + hh * 64 + d] = f2bf(oacc[nd][reg]);
        }
}

// ---------------- launch ----------------
extern "C" void kernel_launch(void* const* d_in, const int* in_sizes, int n_in,
                              void* d_out, int out_size, void* d_ws, size_t ws_size,
                              hipStream_t stream) {
    const float* queries = (const float*)d_in[0];
    const float* keys    = (const float*)d_in[1];
    const float* values  = (const float*)d_in[2];
    const unsigned char* mask = (const unsigned char*)d_in[3];
    const float* context = (const float*)d_in[4];
    const float* Wq  = (const float*)d_in[5];  const float* bq  = (const float*)d_in[6];
    const float* Wk  = (const float*)d_in[7];  const float* bk  = (const float*)d_in[8];
    const float* Wv  = (const float*)d_in[9];  const float* bv  = (const float*)d_in[10];
    const float* Wqb = (const float*)d_in[11]; const float* bqb = (const float*)d_in[12];
    const float* Wkg = (const float*)d_in[13]; const float* bkg = (const float*)d_in[14];
    const float* Wvb = (const float*)d_in[15]; const float* bvb = (const float*)d_in[16];
    const float* Wo  = (const float*)d_in[17]; const float* bo  = (const float*)d_in[18];

    unsigned short* ws = (unsigned short*)d_ws;
    unsigned short* xq = ws + OFF_XQ;
    unsigned short* xk = ws + OFF_XK;
    unsigned short* xv = ws + OFF_XV;
    unsigned short* xc = ws + OFF_XC;
    unsigned short* wt = ws + OFF_WT;
    unsigned short* Qh = ws + OFF_QH;
    unsigned short* Kh = ws + OFF_KH;
    unsigned short* Vh = ws + OFF_VH;
    unsigned short* Oh = ws + OFF_OH;
    unsigned short* sgT = ws + OFF_OH;                               // gate factors; Oh reused later
    unsigned short* VhT = ws + OFF_XQ;                               // reuse xq after projections
    unsigned long long* mbits = (unsigned long long*)(ws + OFF_XV);  // reuse xv after V proj

    float* out0  = (float*)d_out;
    float* attnW = out0 + 4194304;

    P4 acts; acts.p[0] = queries; acts.p[1] = keys; acts.p[2] = values; acts.p[3] = context;
    cvt4<<<dim3(2048, 4), 256, 0, stream>>>(acts, xq);

    P7 wts; wts.p[0] = Wq; wts.p[1] = Wqb; wts.p[2] = Wk; wts.p[3] = Wkg;
    wts.p[4] = Wv; wts.p[5] = Wvb; wts.p[6] = Wo;
    wtr<<<dim3(32, 32, 7), 256, 0, stream>>>(wts, wt);

    // gate factors first: sgT[n][m] = sigmoid(Xc@Wkg + bkg)
    proj_gate_sig<<<dim3(16, 32), 256, 0, stream>>>(xc, wt + 3u * 1048576u, bkg, sgT);

    ProjArgs pa;
    // z=0: Qh = ([Xq|Xc] @ [Wq;Wqb] + bq + bqb) * (0.125*log2e)  -> base-2 softmax
    pa.d[0] = { xq, xc, wt, wt + 1048576u, bq, bqb, Qh, 0.18033688f, 0, 64 };
    // z=1: Vh = [Xv|Xc] @ [Wv;Wvb] + bv + bvb
    pa.d[1] = { xv, xc, wt + 4u * 1048576u, wt + 5u * 1048576u, bv, bvb, Vh, 1.0f, 0, 64 };
    // z=2: Kh = (Xk@Wk + bk) * sgT   (A1=A0, B1=B0: staging branch-free, 32 steps)
    pa.d[2] = { xk, xk, wt + 2u * 1048576u, wt + 2u * 1048576u, bk, bk, Kh, 1.0f, 1, 32 };
    proj_all<<<dim3(8, 32, 3), 256, 0, stream>>>(pa, sgT);

    vtr<<<dim3(32, 32), 256, 0, stream>>>(Vh, VhT);            // xq region now free
    mpack<<<dim3(32768), 256, 0, stream>>>(mask, mbits);       // xv region now free

    attn_fused<<<dim3(1024), 256, 0, stream>>>(Qh, Kh, VhT, mbits, attnW, Oh);

    gemm_out<<<dim3(16, 32), 256, 0, stream>>>(Oh, wt + 6u * 1048576u, bo, out0);
}

// Round 18
// 344.282 us; speedup vs baseline: 1.0602x; 1.0242x over previous
//
#include <hip/hip_runtime.h>

typedef __attribute__((ext_vector_type(8))) short  s16x8;
typedef __attribute__((ext_vector_type(8))) unsigned short u16x8;
typedef __attribute__((ext_vector_type(4))) float  f32x4;

#define D_MODEL 1024
#define N_HEADS 16
#define D_HEAD  64
#define BATCH   2
#define SEQ     2048
#define M_TOK   4096   // BATCH*SEQ

// ---------------- ws layout (ushort element offsets) ----------------
#define OFF_XQ  0u
#define OFF_XK  4194304u
#define OFF_XV  8388608u      // reused for mask bitmask after V projection
#define OFF_XC  12582912u
#define OFF_WT  16777216u     // 7 x 1048576 : Wq,Wqb,Wk,Wkg,Wv,Wvb,Wo (transposed [n][k])
#define OFF_QH  24117248u     // [B][H][T][64] bf16 (pre-scaled by log2e/8)
#define OFF_KH  28311552u
#define OFF_VH  32505856u     // VhT [bh][d][s] written DIRECTLY by proj_all z=1
#define OFF_OH  36700160u     // [B*T][1024] bf16; ALSO sgT[n][m] before attn runs

__device__ __forceinline__ unsigned short f2bf(float f) {
    unsigned int u = __builtin_bit_cast(unsigned int, f);
    u += 0x7FFFu + ((u >> 16) & 1u);
    return (unsigned short)(u >> 16);
}

// single-instruction packed f32x2 -> bf16x2 (RNE); low half = a
__device__ __forceinline__ unsigned int cvtpk(float a, float b) {
    unsigned int r;
    asm("v_cvt_pk_bf16_f32 %0, %1, %2" : "=v"(r) : "v"(a), "v"(b));
    return r;
}

__device__ __forceinline__ float bf2f(unsigned short u) {
    return __builtin_bit_cast(float, (unsigned int)u << 16);
}

__device__ __forceinline__ void gload16(const void* g, void* l) {
    __builtin_amdgcn_global_load_lds(
        (const __attribute__((address_space(1))) unsigned int*)g,
        (__attribute__((address_space(3))) unsigned int*)l, 16, 0, 0);
}

__device__ __forceinline__ f32x4 mfma16(s16x8 a, s16x8 b, f32x4 c) {
    return __builtin_amdgcn_mfma_f32_16x16x32_bf16(a, b, c, 0, 0, 0);
}

__device__ __forceinline__ f32x4 zero4() {
    f32x4 z; z[0] = 0.f; z[1] = 0.f; z[2] = 0.f; z[3] = 0.f; return z;
}

// ---------------- conversion kernels ----------------
struct P4 { const float* p[4]; };
struct P7 { const float* p[7]; };

__global__ __launch_bounds__(256) void cvt4(P4 srcs, unsigned short* dst) {
    const int a = blockIdx.y;
    const float* s = srcs.p[a];
    unsigned short* d = dst + ((size_t)a << 22);
    const size_t i = (((size_t)blockIdx.x << 8) + threadIdx.x) << 3;
    const float4 v0 = *(const float4*)(s + i);
    const float4 v1 = *(const float4*)(s + i + 4);
    u16x8 o;
    o[0] = f2bf(v0.x); o[1] = f2bf(v0.y); o[2] = f2bf(v0.z); o[3] = f2bf(v0.w);
    o[4] = f2bf(v1.x); o[5] = f2bf(v1.y); o[6] = f2bf(v1.z); o[7] = f2bf(v1.w);
    *(u16x8*)(d + i) = o;
}

// transpose weights: Wt[n][k] = W[k][n], f32 -> bf16
__global__ __launch_bounds__(256) void wtr(P7 srcs, unsigned short* dst) {
    const int z = blockIdx.z;
    const float* W = srcs.p[z];
    unsigned short* Wt = dst + ((size_t)z << 20);
    __shared__ float T[32][33];
    const int t = threadIdx.x;
    const int r = t >> 3, c4 = (t & 7) << 2;
    const int kt = blockIdx.y << 5, nt = blockIdx.x << 5;
    const float4 v = *(const float4*)(W + ((size_t)(kt + r) << 10) + nt + c4);
    T[r][c4] = v.x; T[r][c4 + 1] = v.y; T[r][c4 + 2] = v.z; T[r][c4 + 3] = v.w;
    __syncthreads();
    ushort4 o;
    o.x = f2bf(T[c4 + 0][r]); o.y = f2bf(T[c4 + 1][r]);
    o.z = f2bf(T[c4 + 2][r]); o.w = f2bf(T[c4 + 3][r]);
    *(ushort4*)(Wt + ((size_t)(nt + r) << 10) + kt + c4) = o;
}

// pack mask to bits: bit i of mb[w] = mask[w*64+i] != 0. Autodetect int32 vs byte.
__global__ __launch_bounds__(256) void mpack(const unsigned char* __restrict__ maskp,
                                             unsigned long long* __restrict__ mb) {
    const unsigned int probe = ((const unsigned int*)maskp)[threadIdx.x & 63];
    const bool isInt = __all(probe <= 1u);
    const size_t i = ((size_t)blockIdx.x << 8) + threadIdx.x;
    bool v;
    if (isInt) v = ((const int*)maskp)[i] != 0;
    else       v = maskp[i] != 0;
    const unsigned long long bal = __ballot(v);
    if ((threadIdx.x & 63) == 0) mb[i >> 6] = bal;
}

// ---------------- gate-sigmoid GEMM: sgT[n][m] = bf16(sigmoid(Xc@Wkg + bkg)) ----------
// 128x64 tile, K=1024 (32 steps), 2-phase dbuf.
__global__ __launch_bounds__(256) void proj_gate_sig(
    const unsigned short* __restrict__ A, const unsigned short* __restrict__ Bt,
    const float* __restrict__ bias, unsigned short* __restrict__ sgT)
{
    __shared__ unsigned short Al[2][128 * 32];
    __shared__ unsigned short Bl[2][64 * 32];
    const int tid = threadIdx.x;
    const int wid = tid >> 6, lane = tid & 63;
    const int lo = lane & 15, hi = lane >> 4;
    const int wr = wid >> 1, wc = wid & 1;
    const int m0 = blockIdx.y << 7, n0 = blockIdx.x << 6;

    auto stageT = [&](int t) {
        const int bufi = t & 1;
        const int k0 = t << 5;
        #pragma unroll
        for (int it = 0; it < 2; ++it) {
            const int c = it * 256 + tid;
            const int r = c >> 2, j = c & 3;
            gload16(A + ((size_t)(m0 + r) << 10) + k0 + j * 8, &Al[bufi][c * 8]);
        }
        const int rb = tid >> 2, jb = tid & 3;
        gload16(Bt + ((size_t)(n0 + rb) << 10) + k0 + jb * 8, &Bl[bufi][tid * 8]);
    };

    f32x4 acc[4][2];
    #pragma unroll
    for (int i = 0; i < 4; ++i)
        #pragma unroll
        for (int j = 0; j < 2; ++j) acc[i][j] = zero4();

    stageT(0);
    for (int t = 0; t < 32; ++t) {
        __syncthreads();
        if (t < 31) stageT(t + 1);
        const int bufi = t & 1;
        s16x8 af[4], bfr[2];
        #pragma unroll
        for (int mi = 0; mi < 4; ++mi)
            af[mi] = *(const s16x8*)&Al[bufi][(wr * 64 + mi * 16 + lo) * 32 + hi * 8];
        #pragma unroll
        for (int ni = 0; ni < 2; ++ni)
            bfr[ni] = *(const s16x8*)&Bl[bufi][(wc * 32 + ni * 16 + lo) * 32 + hi * 8];
        __builtin_amdgcn_s_setprio(1);
        #pragma unroll
        for (int mi = 0; mi < 4; ++mi)
            #pragma unroll
            for (int ni = 0; ni < 2; ++ni)
                acc[mi][ni] = mfma16(af[mi], bfr[ni], acc[mi][ni]);
        __builtin_amdgcn_s_setprio(0);
    }

    #pragma unroll
    for (int mi = 0; mi < 4; ++mi)
        #pragma unroll
        for (int ni = 0; ni < 2; ++ni) {
            const int n = n0 + wc * 32 + ni * 16 + lo;
            const float bb = bias[n];
            const int mb = m0 + wr * 64 + mi * 16 + hi * 4;
            ushort4 o;
            unsigned short* op = (unsigned short*)&o;
            #pragma unroll
            for (int reg = 0; reg < 4; ++reg) {
                const float g = acc[mi][ni][reg] + bb;
                op[reg] = f2bf(1.0f / (1.0f + __expf(-g)));
            }
            *(ushort4*)(sgT + (size_t)n * 4096 + mb) = o;
        }
}

// ---------------- fused projection GEMMs (m97 128x128, uniform single acc) ------------
// z0: Qh = ([Xq|Xc]@[Wq;Wqb] + bq+bqb)*scale (K=2048), layout [B][H][T][64].
// z1: VhT = ([Xv|Xc]@[Wv;Wvb] + bv+bvb)  written TRANSPOSED [bh][d][s] (vtr fused;
//     4 regs = 4 consecutive tokens = contiguous ushort4 store).
// z2: Kh = (Xk@Wk + bk) * sgT  (K=1024; A1=A0,B1=B0 so staging branch-free).
struct ProjDesc {
    const unsigned short *A0, *A1, *B0, *B1;
    const float *b0, *b1;
    unsigned short* dst;
    float scale;
    int gate;
    int nsteps;
    int vtout;    // 1: write transposed [bh][d][s]
};
struct ProjArgs { ProjDesc d[3]; };

__global__ __launch_bounds__(256) void proj_all(ProjArgs pa, const unsigned short* __restrict__ sgT) {
    const ProjDesc P = pa.d[blockIdx.z];
    __shared__ unsigned short Al[2][128 * 32];   // 2 x 8 KB
    __shared__ unsigned short Bl[2][128 * 32];   // 2 x 8 KB
    const int tid = threadIdx.x;
    const int wid = tid >> 6, lane = tid & 63;
    const int lo = lane & 15, hi = lane >> 4;
    const int wr = wid >> 1, wc = wid & 1;
    const int m0 = blockIdx.y << 7, n0 = blockIdx.x << 7;

    auto stageT = [&](int t) {
        const int bufi = t & 1;
        const unsigned short* As = (t < 32) ? P.A0 : P.A1;
        const unsigned short* Bs = (t < 32) ? P.B0 : P.B1;
        const int k0 = (t & 31) << 5;
        #pragma unroll
        for (int it = 0; it < 2; ++it) {
            const int c = it * 256 + tid;
            const int r = c >> 2, j = c & 3;
            gload16(As + ((size_t)(m0 + r) << 10) + k0 + j * 8, &Al[bufi][c * 8]);
            gload16(Bs + ((size_t)(n0 + r) << 10) + k0 + j * 8, &Bl[bufi][c * 8]);
        }
    };

    f32x4 acc[4][4];
    #pragma unroll
    for (int i = 0; i < 4; ++i)
        #pragma unroll
        for (int j = 0; j < 4; ++j) acc[i][j] = zero4();

    const int nsteps = P.nsteps;
    stageT(0);
    for (int t = 0; t < nsteps; ++t) {
        __syncthreads();
        if (t + 1 < nsteps) stageT(t + 1);
        const int bufi = t & 1;
        s16x8 af[4], bfr[4];
        #pragma unroll
        for (int mi = 0; mi < 4; ++mi)
            af[mi] = *(const s16x8*)&Al[bufi][(wr * 64 + mi * 16 + lo) * 32 + hi * 8];
        #pragma unroll
        for (int ni = 0; ni < 4; ++ni)
            bfr[ni] = *(const s16x8*)&Bl[bufi][(wc * 64 + ni * 16 + lo) * 32 + hi * 8];
        __builtin_amdgcn_s_setprio(1);
        #pragma unroll
        for (int mi = 0; mi < 4; ++mi)
            #pragma unroll
            for (int ni = 0; ni < 4; ++ni)
                acc[mi][ni] = mfma16(af[mi], bfr[ni], acc[mi][ni]);
        __builtin_amdgcn_s_setprio(0);
    }

    #pragma unroll
    for (int mi = 0; mi < 4; ++mi)
        #pragma unroll
        for (int ni = 0; ni < 4; ++ni) {
            const int n = n0 + wc * 64 + ni * 16 + lo;
            const float b0 = P.b0[n];
            const float b1 = P.b1[n];
            const int h = n >> 6, d = n & 63;
            const int mb = m0 + wr * 64 + mi * 16 + hi * 4;
            ushort4 sgv;
            if (P.gate) sgv = *(const ushort4*)(sgT + (size_t)n * 4096 + mb);
            const unsigned short* sp = (const unsigned short*)&sgv;
            if (P.vtout) {
                // 4 regs = tokens t..t+3 at fixed (b,h,d): contiguous in [bh][d][s]
                const int bb = mb >> 11, tt = mb & 2047;
                ushort4 o;
                unsigned short* op = (unsigned short*)&o;
                #pragma unroll
                for (int reg = 0; reg < 4; ++reg)
                    op[reg] = f2bf(acc[mi][ni][reg] + b0 + b1);
                *(ushort4*)(P.dst + (((size_t)((bb * 16 + h) * 64 + d)) << 11) + tt) = o;
            } else {
                #pragma unroll
                for (int reg = 0; reg < 4; ++reg) {
                    const int m = mb + reg;
                    const int b = m >> 11, t = m & 2047;
                    float val;
                    if (P.gate) val = (acc[mi][ni][reg] + b0) * bf2f(sp[reg]);
                    else        val = (acc[mi][ni][reg] + b0 + b1) * P.scale;
                    P.dst[((size_t)((b * 16 + h) * 2048 + t) << 6) + d] = f2bf(val);
                }
            }
        }
}

// out0 = Oh @ Wo + bo  (f32 output), 128x64 tile, 2-phase double-buffered
__global__ __launch_bounds__(256) void gemm_out(
    const unsigned short* __restrict__ A, const unsigned short* __restrict__ Bt,
    const float* __restrict__ bias, float* __restrict__ out)
{
    __shared__ unsigned short Al[2][128 * 32];
    __shared__ unsigned short Bl[2][64 * 32];
    const int tid = threadIdx.x;
    const int wid = tid >> 6, lane = tid & 63;
    const int lo = lane & 15, hi = lane >> 4;
    const int wr = wid >> 1, wc = wid & 1;
    const int m0 = blockIdx.y << 7, n0 = blockIdx.x << 6;

    auto stageT = [&](int t) {
        const int bufi = t & 1;
        const int k0 = t << 5;
        #pragma unroll
        for (int it = 0; it < 2; ++it) {
            const int c = it * 256 + tid;
            const int r = c >> 2, j = c & 3;
            gload16(A + ((size_t)(m0 + r) << 10) + k0 + j * 8, &Al[bufi][c * 8]);
        }
        const int rb = tid >> 2, jb = tid & 3;
        gload16(Bt + ((size_t)(n0 + rb) << 10) + k0 + jb * 8, &Bl[bufi][tid * 8]);
    };

    f32x4 acc[4][2];
    #pragma unroll
    for (int i = 0; i < 4; ++i)
        #pragma unroll
        for (int j = 0; j < 2; ++j) acc[i][j] = zero4();

    stageT(0);
    for (int t = 0; t < 32; ++t) {
        __syncthreads();
        if (t < 31) stageT(t + 1);
        const int bufi = t & 1;
        s16x8 af[4], bfr[2];
        #pragma unroll
        for (int mi = 0; mi < 4; ++mi)
            af[mi] = *(const s16x8*)&Al[bufi][(wr * 64 + mi * 16 + lo) * 32 + hi * 8];
        #pragma unroll
        for (int ni = 0; ni < 2; ++ni)
            bfr[ni] = *(const s16x8*)&Bl[bufi][(wc * 32 + ni * 16 + lo) * 32 + hi * 8];
        __builtin_amdgcn_s_setprio(1);
        #pragma unroll
        for (int mi = 0; mi < 4; ++mi)
            #pragma unroll
            for (int ni = 0; ni < 2; ++ni)
                acc[mi][ni] = mfma16(af[mi], bfr[ni], acc[mi][ni]);
        __builtin_amdgcn_s_setprio(0);
    }

    #pragma unroll
    for (int mi = 0; mi < 4; ++mi)
        #pragma unroll
        for (int ni = 0; ni < 2; ++ni) {
            const int n = n0 + wc * 32 + ni * 16 + lo;
            const float bb = bias[n];
            #pragma unroll
            for (int reg = 0; reg < 4; ++reg) {
                const int m = m0 + wr * 64 + mi * 16 + hi * 4 + reg;
                out[((size_t)m << 10) + n] = acc[mi][ni][reg] + bb;
            }
        }
}

// ---------------- fused attention (R5/R11 structure: best measured) ----------
__global__ __launch_bounds__(256, 4) void attn_fused(
    const unsigned short* __restrict__ Qh, const unsigned short* __restrict__ Kh,
    const unsigned short* __restrict__ VhT, const unsigned long long* __restrict__ mbits,
    float* __restrict__ attnW, unsigned short* __restrict__ Oh)
{
    __shared__ unsigned short Ks[2][4096];   // [64 s][64 d], 16B chunks XOR-swizzled by row&7
    __shared__ unsigned short Vs[2][4096];   // [64 d][64 s], same swizzle
    __shared__ unsigned short Ps[4][1024];   // per-wave P^T [16 q][64 s]

    const int tid = threadIdx.x;
    const int wid = tid >> 6, lane = tid & 63;
    const int lo = lane & 15, hi = lane >> 4;

    const int wg = blockIdx.x;
    const int gid = (wg & 7) * 128 + (wg >> 3);
    const int bh = gid >> 5, lt = gid & 31;
    const int b = bh >> 4, hh = bh & 15;
    const int l0 = lt << 6;

    const unsigned short* Qp = Qh + ((size_t)bh * 2048 + l0) * 64;
    const unsigned short* Kp = Kh + (size_t)bh * 2048 * 64;
    const unsigned short* Vp = VhT + (size_t)bh * 64 * 2048;

    const int q = wid * 16 + lo;   // this thread's q row
    float* Wrow = attnW + ((size_t)bh * 2048 + l0 + q) * 2048 + hi * 4;
    const unsigned long long* mq = mbits + ((size_t)b * 2048 + l0 + q) * 32;

    // Q fragment (B-operand): rows q, pre-scaled by log2e/8 at projection
    s16x8 qf[2];
    {
        const unsigned short* qr = Qp + (size_t)q * 64 + hi * 8;
        qf[0] = *(const s16x8*)qr;
        qf[1] = *(const s16x8*)(qr + 32);
    }

    auto stageK = [&](int st, int bufi) {
        const unsigned short* src = Kp + (size_t)(st << 6) * 64;
        #pragma unroll
        for (int it = 0; it < 2; ++it) {
            const int c = it * 256 + tid;
            const int r = c >> 3, j = c & 7;
            gload16(src + (size_t)r * 64 + ((j ^ (r & 7)) << 3), &Ks[bufi][c * 8]);
        }
    };
    auto stageV = [&](int st, int bufi) {
        const unsigned short* src = Vp + (st << 6);
        #pragma unroll
        for (int it = 0; it < 2; ++it) {
            const int c = it * 256 + tid;
            const int r = c >> 3, j = c & 7;
            gload16(src + (size_t)r * 2048 + ((j ^ (r & 7)) << 3), &Vs[bufi][c * 8]);
        }
    };

    // ================= pass 0: row sums of 2^s ====
    float lsum = 0.f;
    stageK(0, 0);
    __syncthreads();
    for (int st = 0; st < 32; ++st) {
        const int cur = st & 1;
        if (st < 31) stageK(st + 1, cur ^ 1);

        const unsigned long long mrow = mq[st] >> (hi * 4);
        f32x4 sf[4];
        #pragma unroll
        for (int ni = 0; ni < 4; ++ni) sf[ni] = zero4();
        __builtin_amdgcn_s_setprio(1);
        #pragma unroll
        for (int ks = 0; ks < 2; ++ks)
            #pragma unroll
            for (int ni = 0; ni < 4; ++ni) {
                const int rn = ni * 16 + lo;
                const s16x8 kf = *(const s16x8*)&Ks[cur][rn * 64 + (((hi + ks * 4) ^ (rn & 7)) << 3)];
                sf[ni] = mfma16(kf, qf[ks], sf[ni]);   // S^T: row=s, col=q
            }
        __builtin_amdgcn_s_setprio(0);
        #pragma unroll
        for (int ni = 0; ni < 4; ++ni)
            #pragma unroll
            for (int reg = 0; reg < 4; ++reg) {
                const unsigned int bit = (unsigned int)(mrow >> (ni * 16 + reg)) & 1u;
                lsum += bit ? 0.f : exp2f(sf[ni][reg]);
            }
        __syncthreads();
    }
    lsum += __shfl_xor(lsum, 16);
    lsum += __shfl_xor(lsum, 32);
    const float il = 1.0f / lsum;

    // ================= pass 1: normalized weights + PV ================
    f32x4 oacc[4];
    #pragma unroll
    for (int nd = 0; nd < 4; ++nd) oacc[nd] = zero4();

    stageK(0, 0);
    stageV(0, 0);
    __syncthreads();
    for (int st = 0; st < 32; ++st) {
        const int cur = st & 1;
        if (st < 31) { stageK(st + 1, cur ^ 1); stageV(st + 1, cur ^ 1); }

        const unsigned long long mrow = mq[st] >> (hi * 4);
        f32x4 sf[4];
        #pragma unroll
        for (int ni = 0; ni < 4; ++ni) sf[ni] = zero4();
        __builtin_amdgcn_s_setprio(1);
        #pragma unroll
        for (int ks = 0; ks < 2; ++ks)
            #pragma unroll
            for (int ni = 0; ni < 4; ++ni) {
                const int rn = ni * 16 + lo;
                const s16x8 kf = *(const s16x8*)&Ks[cur][rn * 64 + (((hi + ks * 4) ^ (rn & 7)) << 3)];
                sf[ni] = mfma16(kf, qf[ks], sf[ni]);
            }
        __builtin_amdgcn_s_setprio(0);

        #pragma unroll
        for (int ni = 0; ni < 4; ++ni) {
            f32x4 wv;
            #pragma unroll
            for (int reg = 0; reg < 4; ++reg) {
                const unsigned int bit = (unsigned int)(mrow >> (ni * 16 + reg)) & 1u;
                const float e = bit ? 0.f : exp2f(sf[ni][reg]);
                wv[reg] = e * il;
            }
            __builtin_nontemporal_store(wv, (f32x4*)(Wrow + (size_t)st * 64 + ni * 16));
            const unsigned int p01 = cvtpk(wv[0], wv[1]);
            const unsigned int p23 = cvtpk(wv[2], wv[3]);
            *(uint2*)((char*)&Ps[wid][0] + lo * 128 + ((ni * 32 + hi * 8) ^ ((lo & 7) << 4))) =
                make_uint2(p01, p23);
        }

        // PV: O[q][d] += P[q][s] V[s][d]
        __builtin_amdgcn_s_setprio(1);
        #pragma unroll
        for (int ks = 0; ks < 2; ++ks) {
            const s16x8 pf = *(const s16x8*)((const char*)&Ps[wid][0] +
                lo * 128 + ((ks * 64 + hi * 16) ^ ((lo & 7) << 4)));
            #pragma unroll
            for (int nd = 0; nd < 4; ++nd) {
                const int rv = nd * 16 + lo;
                const s16x8 vf = *(const s16x8*)&Vs[cur][rv * 64 + (((hi + ks * 4) ^ (rv & 7)) << 3)];
                oacc[nd] = mfma16(pf, vf, oacc[nd]);
            }
        }
        __builtin_amdgcn_s_setprio(0);
        __syncthreads();
    }

    // ---- epilogue: Oh[b*2048 + l][h*64 + d] ----
    #pragma unroll
    for (int nd = 0; nd < 4; ++nd)
        #pragma unroll
        for (int reg = 0; reg < 4; ++reg) {
            const int rl = wid * 16 + hi * 4 + reg;
            const int d = nd * 16 + lo;
            Oh[((size_t)(b * 2048 + l0 + rl) << 10) + hh * 64 + d] = f2bf(oacc[nd][reg]);
        }
}

// ---------------- launch ----------------
extern "C" void kernel_launch(void* const* d_in, const int* in_sizes, int n_in,
                              void* d_out, int out_size, void* d_ws, size_t ws_size,
                              hipStream_t stream) {
    const float* queries = (const float*)d_in[0];
    const float* keys    = (const float*)d_in[1];
    const float* values  = (const float*)d_in[2];
    const unsigned char* mask = (const unsigned char*)d_in[3];
    const float* context = (const float*)d_in[4];
    const float* Wq  = (const float*)d_in[5];  const float* bq  = (const float*)d_in[6];
    const float* Wk  = (const float*)d_in[7];  const float* bk  = (const float*)d_in[8];
    const float* Wv  = (const float*)d_in[9];  const float* bv  = (const float*)d_in[10];
    const float* Wqb = (const float*)d_in[11]; const float* bqb = (const float*)d_in[12];
    const float* Wkg = (const float*)d_in[13]; const float* bkg = (const float*)d_in[14];
    const float* Wvb = (const float*)d_in[15]; const float* bvb = (const float*)d_in[16];
    const float* Wo  = (const float*)d_in[17]; const float* bo  = (const float*)d_in[18];

    unsigned short* ws = (unsigned short*)d_ws;
    unsigned short* xq = ws + OFF_XQ;
    unsigned short* xk = ws + OFF_XK;
    unsigned short* xv = ws + OFF_XV;
    unsigned short* xc = ws + OFF_XC;
    unsigned short* wt = ws + OFF_WT;
    unsigned short* Qh = ws + OFF_QH;
    unsigned short* Kh = ws + OFF_KH;
    unsigned short* VhT = ws + OFF_VH;                               // [bh][d][s], written by proj z=1
    unsigned short* Oh = ws + OFF_OH;
    unsigned short* sgT = ws + OFF_OH;                               // gate factors; Oh reused later
    unsigned long long* mbits = (unsigned long long*)(ws + OFF_XV);  // reuse xv after V proj

    float* out0  = (float*)d_out;
    float* attnW = out0 + 4194304;

    P4 acts; acts.p[0] = queries; acts.p[1] = keys; acts.p[2] = values; acts.p[3] = context;
    cvt4<<<dim3(2048, 4), 256, 0, stream>>>(acts, xq);

    P7 wts; wts.p[0] = Wq; wts.p[1] = Wqb; wts.p[2] = Wk; wts.p[3] = Wkg;
    wts.p[4] = Wv; wts.p[5] = Wvb; wts.p[6] = Wo;
    wtr<<<dim3(32, 32, 7), 256, 0, stream>>>(wts, wt);

    // gate factors first: sgT[n][m] = sigmoid(Xc@Wkg + bkg)
    proj_gate_sig<<<dim3(16, 32), 256, 0, stream>>>(xc, wt + 3u * 1048576u, bkg, sgT);

    ProjArgs pa;
    // z=0: Qh = ([Xq|Xc] @ [Wq;Wqb] + bq + bqb) * (0.125*log2e)  -> base-2 softmax
    pa.d[0] = { xq, xc, wt, wt + 1048576u, bq, bqb, Qh, 0.18033688f, 0, 64, 0 };
    // z=1: VhT = [Xv|Xc] @ [Wv;Wvb] + bv + bvb, written transposed (vtr fused)
    pa.d[1] = { xv, xc, wt + 4u * 1048576u, wt + 5u * 1048576u, bv, bvb, VhT, 1.0f, 0, 64, 1 };
    // z=2: Kh = (Xk@Wk + bk) * sgT   (A1=A0, B1=B0: staging branch-free, 32 steps)
    pa.d[2] = { xk, xk, wt + 2u * 1048576u, wt + 2u * 1048576u, bk, bk, Kh, 1.0f, 1, 32, 0 };
    proj_all<<<dim3(8, 32, 3), 256, 0, stream>>>(pa, sgT);

    mpack<<<dim3(32768), 256, 0, stream>>>(mask, mbits);       // xv region reused

    attn_fused<<<dim3(1024), 256, 0, stream>>>(Qh, Kh, VhT, mbits, attnW, Oh);

    gemm_out<<<dim3(16, 32), 256, 0, stream>>>(Oh, wt + 6u * 1048576u, bo, out0);
}